// Round 2
// baseline (512.189 us; speedup 1.0000x reference)
//
#include <hip/hip_runtime.h>

typedef unsigned short u16;
typedef unsigned int u32;
typedef __bf16 bf16x8 __attribute__((ext_vector_type(8)));
typedef float f32x4 __attribute__((ext_vector_type(4)));
typedef u16 u16x8 __attribute__((ext_vector_type(8)));
typedef u16 u16x2 __attribute__((ext_vector_type(2)));

__device__ __forceinline__ float bf2f(u16 u) {
    union { u32 u; float f; } c; c.u = ((u32)u) << 16; return c.f;
}
__device__ __forceinline__ u16 f2bf(float f) {
    union { float f; u32 u; } c; c.f = f;
    u32 r = c.u + 0x7fffu + ((c.u >> 16) & 1u);
    return (u16)(r >> 16);
}
__device__ __forceinline__ bf16x8 ld_frag(const u16* p) {
    return *reinterpret_cast<const bf16x8*>(p);
}

// ---------------- K0: transpose weights to [N][K] (K-contiguous), fp32 -> bf16 ----------------
__global__ __launch_bounds__(256) void k_wT(
    const float* __restrict__ qkv_w, const float* __restrict__ proj_w,
    const float* __restrict__ fc1_w, const float* __restrict__ fc2_w,
    u16* __restrict__ qkvT, u16* __restrict__ projT,
    u16* __restrict__ fc1T, u16* __restrict__ fc2T)
{
    int t = blockIdx.x * 256 + threadIdx.x;          // < 65536
    if (t < 49152) { int k = t / 384, n = t % 384; qkvT[n*128 + k] = f2bf(qkv_w[t]); }
    if (t < 16384) { int k = t / 128, n = t % 128; projT[n*128 + k] = f2bf(proj_w[t]); }
    if (t < 65536) { int k = t / 512, n = t % 512; fc1T[n*128 + k] = f2bf(fc1_w[t]); }
    if (t < 65536) { int k = t / 128, n = t % 128; fc2T[n*512 + k] = f2bf(fc2_w[t]); }
}

// ---------------- K1: LN1 + cyclic shift + window partition (fp32 in, bf16 out) ----------------
// one wave per window-token row; 64 lanes x 2 channels
__global__ __launch_bounds__(256) void k_ln1_part(
    const float* __restrict__ x, const float* __restrict__ w, const float* __restrict__ b,
    u16* __restrict__ xw)
{
    int wv = threadIdx.x >> 6, l = threadIdx.x & 63;
    int g = blockIdx.x * 4 + wv;                      // < 100352
    int wi = g / 98, n = g % 98;
    int iw = wi & 7, ih = (wi >> 3) & 7, id = (wi >> 6) & 3, bb = wi >> 8;
    int tw = n % 7, tt = n / 7, th = tt % 7, td = tt / 7;
    int d  = (id * 2 + td + 1) & 7;
    int hh = ih * 7 + th + 3; if (hh >= 56) hh -= 56;
    int ww = iw * 7 + tw + 3; if (ww >= 56) ww -= 56;
    long src = ((((long)bb * 8 + d) * 56 + hh) * 56 + ww) * 128;
    float2 v = *(const float2*)(x + src + l * 2);
    float f0 = v.x, f1 = v.y;
    float s = f0 + f1, s2 = f0*f0 + f1*f1;
    #pragma unroll
    for (int o = 32; o; o >>= 1) { s += __shfl_xor(s, o); s2 += __shfl_xor(s2, o); }
    float mean = s * (1.f/128.f);
    float var  = s2 * (1.f/128.f) - mean*mean;
    float rstd = rsqrtf(var + 1e-5f);
    float y0 = (f0 - mean) * rstd * w[l*2]   + b[l*2];
    float y1 = (f1 - mean) * rstd * w[l*2+1] + b[l*2+1];
    u16x2 o2; o2[0] = f2bf(y0); o2[1] = f2bf(y1);
    *(u16x2*)(xw + (long)g * 128 + l * 2) = o2;
}

// ---------------- K2/K4: GEMM  C[M,N] = A[M,128] @ BT[N,128]^T + bias ----------------
// block: 256 thr (4 waves), tile 128x128, K=128 (single stage)
__global__ __launch_bounds__(256) void k_gemm128(
    const u16* __restrict__ A, const u16* __restrict__ BT,
    const float* __restrict__ bias, u16* __restrict__ out, int ldo)
{
    __shared__ __align__(16) u16 la[128*136];
    __shared__ __align__(16) u16 lb[128*136];
    int m0 = blockIdx.x * 128, n0 = blockIdx.y * 128;
    int t = threadIdx.x;
    #pragma unroll
    for (int i = 0; i < 8; i++) {
        int u = t + i * 256;
        int r = u >> 4, c = u & 15;
        *(u16x8*)&la[r*136 + c*8] = *(const u16x8*)&A [(long)(m0 + r)*128 + c*8];
        *(u16x8*)&lb[r*136 + c*8] = *(const u16x8*)&BT[(long)(n0 + r)*128 + c*8];
    }
    __syncthreads();
    int wv = t >> 6, l = t & 63;
    int wm = (wv & 1) * 64, wn = (wv >> 1) * 64;
    int lr = l & 15, lk = (l >> 4) * 8;
    f32x4 acc[4][4] = {};
    #pragma unroll
    for (int kk = 0; kk < 4; kk++) {
        bf16x8 af[4], bfr[4];
        #pragma unroll
        for (int mi = 0; mi < 4; mi++) af[mi]  = ld_frag(&la[(wm + mi*16 + lr)*136 + kk*32 + lk]);
        #pragma unroll
        for (int ni = 0; ni < 4; ni++) bfr[ni] = ld_frag(&lb[(wn + ni*16 + lr)*136 + kk*32 + lk]);
        #pragma unroll
        for (int mi = 0; mi < 4; mi++)
            #pragma unroll
            for (int ni = 0; ni < 4; ni++)
                acc[mi][ni] = __builtin_amdgcn_mfma_f32_16x16x32_bf16(af[mi], bfr[ni], acc[mi][ni], 0, 0, 0);
    }
    int rb = (l >> 4) * 4;
    #pragma unroll
    for (int mi = 0; mi < 4; mi++)
        #pragma unroll
        for (int ni = 0; ni < 4; ni++) {
            int col = n0 + wn + ni*16 + lr;
            float bv = bias[col];
            #pragma unroll
            for (int r = 0; r < 4; r++) {
                int row = m0 + wm + mi*16 + rb + r;
                out[(long)row*ldo + col] = f2bf(acc[mi][ni][r] + bv);
            }
        }
}

// ---------------- K3: attention per (window, head) ----------------
__global__ __launch_bounds__(256) void k_attn(
    const u16* __restrict__ qkv, u16* __restrict__ attn_out)
{
    __shared__ __align__(16) u16 lq[128*40];
    __shared__ __align__(16) u16 lk[128*40];
    __shared__ __align__(16) u16 lvt[32*136];
    __shared__ __align__(16) float sc[112*132];
    int wi = blockIdx.x, h = blockIdx.y;
    int t = threadIdx.x;
    const long base = (long)wi * 98 * 384 + h * 32;
    // zero the corner of sc that P@V reads but score/softmax phases don't write
    if (t < 224) { int r = 98 + (t >> 4), c = 112 + (t & 15); sc[r*132 + c] = 0.f; }
    // stage q,k (zero-padded to 128 rows)
    #pragma unroll
    for (int i = 0; i < 4; i++) {
        int u = t + i * 256;                  // < 1024
        int mat = u >> 9, row = (u >> 2) & 127, ch = u & 3;
        u16x8 v = {};
        if (row < 98) v = *(const u16x8*)&qkv[base + (long)row*384 + mat*128 + ch*8];
        u16* dst = mat ? lk : lq;
        *(u16x8*)&dst[row*40 + ch*8] = v;
    }
    // stage v transposed: lvt[channel][key]
    #pragma unroll
    for (int i = 0; i < 2; i++) {
        int u = t + i * 256;                  // < 512
        int row = u >> 2, ch = u & 3;
        u16x8 v = {};
        if (row < 98) v = *(const u16x8*)&qkv[base + (long)row*384 + 256 + ch*8];
        #pragma unroll
        for (int j = 0; j < 8; j++) lvt[(ch*8 + j)*136 + row] = v[j];
    }
    __syncthreads();
    int wv = t >> 6, l = t & 63;
    int lr = l & 15, lkk = (l >> 4) * 8;
    const float scale = 0.17677669529663687f;
    // scores = q @ k^T, masked
    for (int tile = wv; tile < 49; tile += 4) {
        int mi = tile / 7, ni = tile % 7;
        bf16x8 qa = ld_frag(&lq[(mi*16 + lr)*40 + lkk]);
        bf16x8 kb = ld_frag(&lk[(ni*16 + lr)*40 + lkk]);
        f32x4 z = {0.f, 0.f, 0.f, 0.f};
        f32x4 s = __builtin_amdgcn_mfma_f32_16x16x32_bf16(qa, kb, z, 0, 0, 0);
        int col = ni*16 + lr;
        #pragma unroll
        for (int r = 0; r < 4; r++) {
            int row = mi*16 + (l >> 4)*4 + r;
            sc[row*132 + col] = (col < 98) ? s[r]*scale : -1e30f;
        }
    }
    __syncthreads();
    // row softmax (rows 0..97), write P (cols 98..127 zeroed)
    for (int r = wv; r < 98; r += 4) {
        float s0 = sc[r*132 + l];
        float s1 = (l < 48) ? sc[r*132 + 64 + l] : -1e30f;
        float m = fmaxf(s0, s1);
        #pragma unroll
        for (int o = 32; o; o >>= 1) m = fmaxf(m, __shfl_xor(m, o));
        float e0 = __expf(s0 - m);
        float e1 = __expf(s1 - m);
        float sum = e0 + e1;
        #pragma unroll
        for (int o = 32; o; o >>= 1) sum += __shfl_xor(sum, o);
        float inv = 1.f / sum;
        sc[r*132 + l]      = e0 * inv;
        sc[r*132 + 64 + l] = (64 + l < 98) ? e1 * inv : 0.f;
    }
    __syncthreads();
    // out = P @ V
    for (int tile = wv; tile < 14; tile += 4) {
        int mi = tile >> 1, ni = tile & 1;
        f32x4 acc = {0.f, 0.f, 0.f, 0.f};
        #pragma unroll
        for (int kk = 0; kk < 4; kk++) {
            const float* pr = &sc[(mi*16 + lr)*132 + kk*32 + lkk];
            bf16x8 pa;
            #pragma unroll
            for (int j = 0; j < 8; j++) pa[j] = (__bf16)pr[j];
            bf16x8 vb = ld_frag(&lvt[(ni*16 + lr)*136 + kk*32 + lkk]);
            acc = __builtin_amdgcn_mfma_f32_16x16x32_bf16(pa, vb, acc, 0, 0, 0);
        }
        #pragma unroll
        for (int r = 0; r < 4; r++) {
            int row = mi*16 + (l >> 4)*4 + r;
            if (row < 98)
                attn_out[((long)wi*98 + row)*128 + h*32 + ni*16 + lr] = f2bf(acc[r]);
        }
    }
}

// ---------------- K5: window reverse + unshift + residual + LN2 ----------------
// x1 (fp32) -> d_out, h2 (bf16) -> ws
__global__ __launch_bounds__(256) void k_res_ln2(
    const u16* __restrict__ proj_out, const float* __restrict__ x,
    const float* __restrict__ w2, const float* __restrict__ b2,
    float* __restrict__ x1, u16* __restrict__ h2out)
{
    int wv = threadIdx.x >> 6, l = threadIdx.x & 63;
    int g = blockIdx.x * 4 + wv;                 // natural token id
    int ww = g % 56; int t1 = g / 56;
    int hh = t1 % 56; int t2 = t1 / 56;
    int d = t2 & 7, bb = t2 >> 3;
    int d2 = (d + 7) & 7;
    int hs = hh - 3; if (hs < 0) hs += 56;
    int ws_ = ww - 3; if (ws_ < 0) ws_ += 56;
    int id = d2 >> 1, td = d2 & 1;
    int ih = hs / 7, th = hs % 7;
    int iw = ws_ / 7, tw = ws_ % 7;
    int wi = ((bb*4 + id)*8 + ih)*8 + iw;
    int n  = (td*7 + th)*7 + tw;
    long prow = ((long)wi*98 + n) * 128;
    long nrow = (long)g * 128;
    u16x2 pv = *(const u16x2*)&proj_out[prow + l*2];
    float2 xv = *(const float2*)&x[nrow + l*2];
    float v0 = bf2f(pv[0]) + xv.x;
    float v1 = bf2f(pv[1]) + xv.y;
    float2 o; o.x = v0; o.y = v1;
    *(float2*)&x1[nrow + l*2] = o;
    float s = v0 + v1, s2 = v0*v0 + v1*v1;
    #pragma unroll
    for (int o2 = 32; o2; o2 >>= 1) { s += __shfl_xor(s, o2); s2 += __shfl_xor(s2, o2); }
    float mean = s * (1.f/128.f), var = s2 * (1.f/128.f) - mean*mean;
    float rstd = rsqrtf(var + 1e-5f);
    float y0 = (v0 - mean)*rstd*w2[l*2]   + b2[l*2];
    float y1 = (v1 - mean)*rstd*w2[l*2+1] + b2[l*2+1];
    u16x2 oh; oh[0] = f2bf(y0); oh[1] = f2bf(y1);
    *(u16x2*)&h2out[nrow + l*2] = oh;
}

// ---------------- K6: fused MLP  out = x1 + fc2(silu(fc1(h2))) ----------------
__global__ __launch_bounds__(256) void k_mlp(
    const u16* __restrict__ h2, const u16* __restrict__ fc1T, const float* __restrict__ b1,
    const u16* __restrict__ fc2T, const float* __restrict__ b2,
    const float* __restrict__ x1, float* __restrict__ out)
{
    __shared__ __align__(16) u16 lh[64*136];
    __shared__ __align__(16) u16 lhid[64*520];
    int m0 = blockIdx.x * 64;
    int t = threadIdx.x;
    #pragma unroll
    for (int i = 0; i < 4; i++) {
        int u = t + i * 256;                 // < 1024
        int r = u >> 4, c = u & 15;
        *(u16x8*)&lh[r*136 + c*8] = *(const u16x8*)&h2[(long)(m0 + r)*128 + c*8];
    }
    __syncthreads();
    int wv = t >> 6, l = t & 63;
    int lr = l & 15, lk = (l >> 4) * 8;
    // phase 1: hidden = silu(h2 @ fc1 + b1) -> LDS
    for (int nt = 0; nt < 8; nt++) {
        int n = wv*8 + nt;                   // n-tile 0..31
        bf16x8 bfr[4];
        #pragma unroll
        for (int kk = 0; kk < 4; kk++)
            bfr[kk] = ld_frag(&fc1T[(n*16 + lr)*128 + kk*32 + lk]);
        float bv = b1[n*16 + lr];
        #pragma unroll
        for (int mt = 0; mt < 4; mt++) {
            f32x4 acc = {0.f, 0.f, 0.f, 0.f};
            #pragma unroll
            for (int kk = 0; kk < 4; kk++) {
                bf16x8 a = ld_frag(&lh[(mt*16 + lr)*136 + kk*32 + lk]);
                acc = __builtin_amdgcn_mfma_f32_16x16x32_bf16(a, bfr[kk], acc, 0, 0, 0);
            }
            #pragma unroll
            for (int r = 0; r < 4; r++) {
                float v = acc[r] + bv;
                v = v / (1.f + __expf(-v));
                lhid[(mt*16 + (l >> 4)*4 + r)*520 + n*16 + lr] = f2bf(v);
            }
        }
    }
    __syncthreads();
    // phase 2: out = hid @ fc2 + b2 + x1
    for (int nt = 0; nt < 2; nt++) {
        int n = wv*2 + nt;                   // n-tile 0..7
        bf16x8 bb[16];
        #pragma unroll
        for (int kk = 0; kk < 16; kk++)
            bb[kk] = ld_frag(&fc2T[(n*16 + lr)*512 + kk*32 + lk]);
        float bv = b2[n*16 + lr];
        #pragma unroll
        for (int mt = 0; mt < 4; mt++) {
            f32x4 acc = {0.f, 0.f, 0.f, 0.f};
            #pragma unroll
            for (int kk = 0; kk < 16; kk++) {
                bf16x8 a = ld_frag(&lhid[(mt*16 + lr)*520 + kk*32 + lk]);
                acc = __builtin_amdgcn_mfma_f32_16x16x32_bf16(a, bb[kk], acc, 0, 0, 0);
            }
            #pragma unroll
            for (int r = 0; r < 4; r++) {
                int row = m0 + mt*16 + (l >> 4)*4 + r;
                int col = n*16 + lr;
                float v = acc[r] + bv + x1[(long)row*128 + col];
                out[(long)row*128 + col] = v;
            }
        }
    }
}

extern "C" void kernel_launch(void* const* d_in, const int* in_sizes, int n_in,
                              void* d_out, int out_size, void* d_ws, size_t ws_size,
                              hipStream_t stream)
{
    const float* x      = (const float*)d_in[0];
    const float* n1w    = (const float*)d_in[1];
    const float* n1b    = (const float*)d_in[2];
    const float* qkv_w  = (const float*)d_in[3];
    const float* qkv_b  = (const float*)d_in[4];
    const float* proj_w = (const float*)d_in[5];
    const float* proj_b = (const float*)d_in[6];
    const float* n2w    = (const float*)d_in[7];
    const float* n2b    = (const float*)d_in[8];
    const float* fc1_w  = (const float*)d_in[9];
    const float* fc1_b  = (const float*)d_in[10];
    const float* fc2_w  = (const float*)d_in[11];
    const float* fc2_b  = (const float*)d_in[12];
    float* out = (float*)d_out;

    u16* ws16  = (u16*)d_ws;
    u16* xw    = ws16;                        // 12,845,056 u16 (later: attn_out, then h2)
    u16* qkv   = xw + 12845056;               // 38,535,168 u16 (later: proj_out)
    u16* qkvT  = qkv + 38535168;              // 49,152
    u16* projT = qkvT + 49152;                // 16,384
    u16* fc1T  = projT + 16384;               // 65,536
    u16* fc2T  = fc1T + 65536;                // 65,536

    k_wT<<<256, 256, 0, stream>>>(qkv_w, proj_w, fc1_w, fc2_w, qkvT, projT, fc1T, fc2T);
    k_ln1_part<<<25088, 256, 0, stream>>>(x, n1w, n1b, xw);
    dim3 gq(784, 3);
    k_gemm128<<<gq, 256, 0, stream>>>(xw, qkvT, qkv_b, qkv, 384);
    dim3 ga(1024, 4);
    k_attn<<<ga, 256, 0, stream>>>(qkv, xw);                        // attn_out -> xw region
    dim3 gp(784, 1);
    k_gemm128<<<gp, 256, 0, stream>>>(xw, projT, proj_b, qkv, 128); // proj_out -> qkv region
    k_res_ln2<<<25088, 256, 0, stream>>>(qkv, x, n2w, n2b, out /*x1 fp32*/, xw /*h2 bf16*/);
    k_mlp<<<1568, 256, 0, stream>>>(xw /*h2*/, fc1T, fc1_b, fc2T, fc2_b, out /*x1*/, out);
}

// Round 3
// 255.216 us; speedup vs baseline: 2.0069x; 2.0069x over previous
//
#include <hip/hip_runtime.h>

typedef unsigned short u16;
typedef unsigned int u32;
typedef __bf16 bf16x8 __attribute__((ext_vector_type(8)));
typedef float f32x4 __attribute__((ext_vector_type(4)));
typedef u16 u16x8 __attribute__((ext_vector_type(8)));
typedef u16 u16x2 __attribute__((ext_vector_type(2)));

__device__ __forceinline__ float bf2f(u16 u) {
    union { u32 u; float f; } c; c.u = ((u32)u) << 16; return c.f;
}
__device__ __forceinline__ u16 f2bf(float f) {
    union { float f; u32 u; } c; c.f = f;
    u32 r = c.u + 0x7fffu + ((c.u >> 16) & 1u);
    return (u16)(r >> 16);
}
__device__ __forceinline__ bf16x8 ld_frag(const u16* p) {
    return *reinterpret_cast<const bf16x8*>(p);
}

// ---------------- K0: transpose weights to [N][K] (K-contiguous), fp32 -> bf16 ----------------
__global__ __launch_bounds__(256) void k_wT(
    const float* __restrict__ qkv_w, const float* __restrict__ proj_w,
    const float* __restrict__ fc1_w, const float* __restrict__ fc2_w,
    u16* __restrict__ qkvT, u16* __restrict__ projT,
    u16* __restrict__ fc1T, u16* __restrict__ fc2T)
{
    int t = blockIdx.x * 256 + threadIdx.x;          // < 65536
    if (t < 49152) { int k = t / 384, n = t % 384; qkvT[n*128 + k] = f2bf(qkv_w[t]); }
    if (t < 16384) { int k = t / 128, n = t % 128; projT[n*128 + k] = f2bf(proj_w[t]); }
    if (t < 65536) { int k = t / 512, n = t % 512; fc1T[n*128 + k] = f2bf(fc1_w[t]); }
    if (t < 65536) { int k = t / 128, n = t % 128; fc2T[n*512 + k] = f2bf(fc2_w[t]); }
}

// ---------------- K1: LN1 + cyclic shift + window partition (fp32 in, bf16 out) ----------------
__global__ __launch_bounds__(256) void k_ln1_part(
    const float* __restrict__ x, const float* __restrict__ w, const float* __restrict__ b,
    u16* __restrict__ xw)
{
    int wv = threadIdx.x >> 6, l = threadIdx.x & 63;
    int g = blockIdx.x * 4 + wv;                      // < 100352
    int wi = g / 98, n = g % 98;
    int iw = wi & 7, ih = (wi >> 3) & 7, id = (wi >> 6) & 3, bb = wi >> 8;
    int tw = n % 7, tt = n / 7, th = tt % 7, td = tt / 7;
    int d  = (id * 2 + td + 1) & 7;
    int hh = ih * 7 + th + 3; if (hh >= 56) hh -= 56;
    int ww = iw * 7 + tw + 3; if (ww >= 56) ww -= 56;
    long src = ((((long)bb * 8 + d) * 56 + hh) * 56 + ww) * 128;
    float2 v = *(const float2*)(x + src + l * 2);
    float f0 = v.x, f1 = v.y;
    float s = f0 + f1, s2 = f0*f0 + f1*f1;
    #pragma unroll
    for (int o = 32; o; o >>= 1) { s += __shfl_xor(s, o); s2 += __shfl_xor(s2, o); }
    float mean = s * (1.f/128.f);
    float var  = s2 * (1.f/128.f) - mean*mean;
    float rstd = rsqrtf(var + 1e-5f);
    float y0 = (f0 - mean) * rstd * w[l*2]   + b[l*2];
    float y1 = (f1 - mean) * rstd * w[l*2+1] + b[l*2+1];
    u16x2 o2; o2[0] = f2bf(y0); o2[1] = f2bf(y1);
    *(u16x2*)(xw + (long)g * 128 + l * 2) = o2;
}

// ---------------- K2/K4: GEMM  C[M,N] = A[M,128] @ BT[N,128]^T + bias ----------------
__global__ __launch_bounds__(256) void k_gemm128(
    const u16* __restrict__ A, const u16* __restrict__ BT,
    const float* __restrict__ bias, u16* __restrict__ out, int ldo)
{
    __shared__ __align__(16) u16 la[128*136];
    __shared__ __align__(16) u16 lb[128*136];
    int m0 = blockIdx.x * 128, n0 = blockIdx.y * 128;
    int t = threadIdx.x;
    #pragma unroll
    for (int i = 0; i < 8; i++) {
        int u = t + i * 256;
        int r = u >> 4, c = u & 15;
        *(u16x8*)&la[r*136 + c*8] = *(const u16x8*)&A [(long)(m0 + r)*128 + c*8];
        *(u16x8*)&lb[r*136 + c*8] = *(const u16x8*)&BT[(long)(n0 + r)*128 + c*8];
    }
    __syncthreads();
    int wv = t >> 6, l = t & 63;
    int wm = (wv & 1) * 64, wn = (wv >> 1) * 64;
    int lr = l & 15, lk = (l >> 4) * 8;
    f32x4 acc[4][4] = {};
    #pragma unroll
    for (int kk = 0; kk < 4; kk++) {
        bf16x8 af[4], bfr[4];
        #pragma unroll
        for (int mi = 0; mi < 4; mi++) af[mi]  = ld_frag(&la[(wm + mi*16 + lr)*136 + kk*32 + lk]);
        #pragma unroll
        for (int ni = 0; ni < 4; ni++) bfr[ni] = ld_frag(&lb[(wn + ni*16 + lr)*136 + kk*32 + lk]);
        #pragma unroll
        for (int mi = 0; mi < 4; mi++)
            #pragma unroll
            for (int ni = 0; ni < 4; ni++)
                acc[mi][ni] = __builtin_amdgcn_mfma_f32_16x16x32_bf16(af[mi], bfr[ni], acc[mi][ni], 0, 0, 0);
    }
    int rb = (l >> 4) * 4;
    #pragma unroll
    for (int mi = 0; mi < 4; mi++)
        #pragma unroll
        for (int ni = 0; ni < 4; ni++) {
            int col = n0 + wn + ni*16 + lr;
            float bv = bias[col];
            #pragma unroll
            for (int r = 0; r < 4; r++) {
                int row = m0 + wm + mi*16 + rb + r;
                out[(long)row*ldo + col] = f2bf(acc[mi][ni][r] + bv);
            }
        }
}

// ---------------- K3: attention per (window, head) — register-resident scores ----------------
// 4 waves; wave wv handles 16-row Q tiles rt = wv, wv+4. Scores in VGPRs, softmax
// via 16-lane shfl_xor (rows live in 16-lane groups per MFMA C layout). P -> small
// per-wave bf16 LDS buffer only for the A-fragment transpose into PV.
__global__ __launch_bounds__(256) void k_attn(
    const u16* __restrict__ qkv, u16* __restrict__ attn_out)
{
    __shared__ __align__(16) u16 lq[128*40];     // [row][k]  (rows >=98 zero)
    __shared__ __align__(16) u16 lk[128*40];     // [row][k]
    __shared__ __align__(16) u16 lvt[32*136];    // [ch][key] (keys >=98 zero)
    __shared__ __align__(16) u16 lp[4][16*136];  // per-wave P tile [row][key]
    int wi = blockIdx.x, h = blockIdx.y;
    int t = threadIdx.x;
    int wv = t >> 6, l = t & 63;
    const long base = (long)wi * 98 * 384 + h * 32;
    u16* lpw = lp[wv];
    // zero this wave's P buffer (cols 112..127 must stay zero for PV chunk 3)
    {
        u16x8 z8 = {};
        for (int i = l; i < 272; i += 64) *(u16x8*)&lpw[i*8] = z8;
    }
    // stage q,k (zero-padded rows)
    #pragma unroll
    for (int i = 0; i < 4; i++) {
        int u = t + i * 256;                  // < 1024
        int mat = u >> 9, row = (u >> 2) & 127, ch = u & 3;
        u16x8 v = {};
        if (row < 98) v = *(const u16x8*)&qkv[base + (long)row*384 + mat*128 + ch*8];
        u16* dst = mat ? lk : lq;
        *(u16x8*)&dst[row*40 + ch*8] = v;
    }
    // stage v transposed: lvt[ch][key], keys 98..127 zero
    #pragma unroll
    for (int i = 0; i < 2; i++) {
        int u = t + i * 256;                  // < 512
        int row = u >> 2, ch = u & 3;
        u16x8 v = {};
        if (row < 98) v = *(const u16x8*)&qkv[base + (long)row*384 + 256 + ch*8];
        #pragma unroll
        for (int j = 0; j < 8; j++) lvt[(ch*8 + j)*136 + row] = v[j];
    }
    __syncthreads();
    int lr = l & 15, lg = l >> 4, lkk = lg * 8;
    const float scale = 0.17677669529663687f;
    for (int rt = wv; rt < 7; rt += 4) {
        bf16x8 qa = ld_frag(&lq[(rt*16 + lr)*40 + lkk]);
        f32x4 s[7];
        #pragma unroll
        for (int ct = 0; ct < 7; ct++) {
            bf16x8 kb = ld_frag(&lk[(ct*16 + lr)*40 + lkk]);
            f32x4 zz = {0.f, 0.f, 0.f, 0.f};
            s[ct] = __builtin_amdgcn_mfma_f32_16x16x32_bf16(qa, kb, zz, 0, 0, 0);
        }
        // scale + key mask (tile 6 covers keys 96..111; valid only lr<2)
        #pragma unroll
        for (int ct = 0; ct < 7; ct++) {
            bool valid = (ct < 6) || (lr < 2);
            #pragma unroll
            for (int r = 0; r < 4; r++)
                s[ct][r] = valid ? s[ct][r] * scale : -1e30f;
        }
        // row softmax: row = rt*16 + lg*4 + r, cols spread over 16 lanes x 7 tiles
        f32x4 mx;
        #pragma unroll
        for (int r = 0; r < 4; r++) {
            float m = s[0][r];
            #pragma unroll
            for (int ct = 1; ct < 7; ct++) m = fmaxf(m, s[ct][r]);
            #pragma unroll
            for (int o = 1; o < 16; o <<= 1) m = fmaxf(m, __shfl_xor(m, o));
            mx[r] = m;
        }
        f32x4 sum = {0.f, 0.f, 0.f, 0.f};
        #pragma unroll
        for (int ct = 0; ct < 7; ct++)
            #pragma unroll
            for (int r = 0; r < 4; r++) {
                s[ct][r] = __expf(s[ct][r] - mx[r]);
                sum[r] += s[ct][r];
            }
        #pragma unroll
        for (int r = 0; r < 4; r++) {
            float ss = sum[r];
            #pragma unroll
            for (int o = 1; o < 16; o <<= 1) ss += __shfl_xor(ss, o);
            sum[r] = 1.f / ss;
        }
        // P (bf16) -> per-wave LDS tile for the A-fragment transpose
        #pragma unroll
        for (int ct = 0; ct < 7; ct++)
            #pragma unroll
            for (int r = 0; r < 4; r++)
                lpw[(lg*4 + r)*136 + ct*16 + lr] = f2bf(s[ct][r] * sum[r]);
        // PV: out[16 x 32] = P[16 x 128pad] @ V[128pad x 32]
        #pragma unroll
        for (int ni = 0; ni < 2; ni++) {
            f32x4 acc = {0.f, 0.f, 0.f, 0.f};
            #pragma unroll
            for (int kk = 0; kk < 4; kk++) {
                bf16x8 pa = ld_frag(&lpw[lr*136 + kk*32 + lkk]);
                bf16x8 vb = ld_frag(&lvt[(ni*16 + lr)*136 + kk*32 + lkk]);
                acc = __builtin_amdgcn_mfma_f32_16x16x32_bf16(pa, vb, acc, 0, 0, 0);
            }
            #pragma unroll
            for (int r = 0; r < 4; r++) {
                int row = rt*16 + lg*4 + r;
                if (row < 98)
                    attn_out[((long)wi*98 + row)*128 + h*32 + ni*16 + lr] = f2bf(acc[r]);
            }
        }
    }
}

// ---------------- K5: window reverse + unshift + residual + LN2 ----------------
// x1 (fp32) -> d_out, h2 (bf16) -> ws
__global__ __launch_bounds__(256) void k_res_ln2(
    const u16* __restrict__ proj_out, const float* __restrict__ x,
    const float* __restrict__ w2, const float* __restrict__ b2,
    float* __restrict__ x1, u16* __restrict__ h2out)
{
    int wv = threadIdx.x >> 6, l = threadIdx.x & 63;
    int g = blockIdx.x * 4 + wv;                 // natural token id
    int ww = g % 56; int t1 = g / 56;
    int hh = t1 % 56; int t2 = t1 / 56;
    int d = t2 & 7, bb = t2 >> 3;
    int d2 = (d + 7) & 7;
    int hs = hh - 3; if (hs < 0) hs += 56;
    int ws_ = ww - 3; if (ws_ < 0) ws_ += 56;
    int id = d2 >> 1, td = d2 & 1;
    int ih = hs / 7, th = hs % 7;
    int iw = ws_ / 7, tw = ws_ % 7;
    int wi = ((bb*4 + id)*8 + ih)*8 + iw;
    int n  = (td*7 + th)*7 + tw;
    long prow = ((long)wi*98 + n) * 128;
    long nrow = (long)g * 128;
    u16x2 pv = *(const u16x2*)&proj_out[prow + l*2];
    float2 xv = *(const float2*)&x[nrow + l*2];
    float v0 = bf2f(pv[0]) + xv.x;
    float v1 = bf2f(pv[1]) + xv.y;
    float2 o; o.x = v0; o.y = v1;
    *(float2*)&x1[nrow + l*2] = o;
    float s = v0 + v1, s2 = v0*v0 + v1*v1;
    #pragma unroll
    for (int o2 = 32; o2; o2 >>= 1) { s += __shfl_xor(s, o2); s2 += __shfl_xor(s2, o2); }
    float mean = s * (1.f/128.f), var = s2 * (1.f/128.f) - mean*mean;
    float rstd = rsqrtf(var + 1e-5f);
    float y0 = (v0 - mean)*rstd*w2[l*2]   + b2[l*2];
    float y1 = (v1 - mean)*rstd*w2[l*2+1] + b2[l*2+1];
    u16x2 oh; oh[0] = f2bf(y0); oh[1] = f2bf(y1);
    *(u16x2*)&h2out[nrow + l*2] = oh;
}

// ---------------- K6: fused MLP  out = x1 + fc2(silu(fc1(h2))) ----------------
__global__ __launch_bounds__(256) void k_mlp(
    const u16* __restrict__ h2, const u16* __restrict__ fc1T, const float* __restrict__ b1,
    const u16* __restrict__ fc2T, const float* __restrict__ b2,
    const float* __restrict__ x1, float* __restrict__ out)
{
    __shared__ __align__(16) u16 lh[64*136];
    __shared__ __align__(16) u16 lhid[64*520];
    int m0 = blockIdx.x * 64;
    int t = threadIdx.x;
    #pragma unroll
    for (int i = 0; i < 4; i++) {
        int u = t + i * 256;                 // < 1024
        int r = u >> 4, c = u & 15;
        *(u16x8*)&lh[r*136 + c*8] = *(const u16x8*)&h2[(long)(m0 + r)*128 + c*8];
    }
    __syncthreads();
    int wv = t >> 6, l = t & 63;
    int lr = l & 15, lk = (l >> 4) * 8;
    // phase 1: hidden = silu(h2 @ fc1 + b1) -> LDS
    for (int nt = 0; nt < 8; nt++) {
        int n = wv*8 + nt;                   // n-tile 0..31
        bf16x8 bfr[4];
        #pragma unroll
        for (int kk = 0; kk < 4; kk++)
            bfr[kk] = ld_frag(&fc1T[(n*16 + lr)*128 + kk*32 + lk]);
        float bv = b1[n*16 + lr];
        #pragma unroll
        for (int mt = 0; mt < 4; mt++) {
            f32x4 acc = {0.f, 0.f, 0.f, 0.f};
            #pragma unroll
            for (int kk = 0; kk < 4; kk++) {
                bf16x8 a = ld_frag(&lh[(mt*16 + lr)*136 + kk*32 + lk]);
                acc = __builtin_amdgcn_mfma_f32_16x16x32_bf16(a, bfr[kk], acc, 0, 0, 0);
            }
            #pragma unroll
            for (int r = 0; r < 4; r++) {
                float v = acc[r] + bv;
                v = v / (1.f + __expf(-v));
                lhid[(mt*16 + (l >> 4)*4 + r)*520 + n*16 + lr] = f2bf(v);
            }
        }
    }
    __syncthreads();
    // phase 2: out = hid @ fc2 + b2 + x1
    for (int nt = 0; nt < 2; nt++) {
        int n = wv*2 + nt;                   // n-tile 0..7
        bf16x8 bb[16];
        #pragma unroll
        for (int kk = 0; kk < 16; kk++)
            bb[kk] = ld_frag(&fc2T[(n*16 + lr)*512 + kk*32 + lk]);
        float bv = b2[n*16 + lr];
        #pragma unroll
        for (int mt = 0; mt < 4; mt++) {
            f32x4 acc = {0.f, 0.f, 0.f, 0.f};
            #pragma unroll
            for (int kk = 0; kk < 16; kk++) {
                bf16x8 a = ld_frag(&lhid[(mt*16 + lr)*520 + kk*32 + lk]);
                acc = __builtin_amdgcn_mfma_f32_16x16x32_bf16(a, bb[kk], acc, 0, 0, 0);
            }
            #pragma unroll
            for (int r = 0; r < 4; r++) {
                int row = m0 + mt*16 + (l >> 4)*4 + r;
                int col = n*16 + lr;
                float v = acc[r] + bv + x1[(long)row*128 + col];
                out[(long)row*128 + col] = v;
            }
        }
    }
}

extern "C" void kernel_launch(void* const* d_in, const int* in_sizes, int n_in,
                              void* d_out, int out_size, void* d_ws, size_t ws_size,
                              hipStream_t stream)
{
    const float* x      = (const float*)d_in[0];
    const float* n1w    = (const float*)d_in[1];
    const float* n1b    = (const float*)d_in[2];
    const float* qkv_w  = (const float*)d_in[3];
    const float* qkv_b  = (const float*)d_in[4];
    const float* proj_w = (const float*)d_in[5];
    const float* proj_b = (const float*)d_in[6];
    const float* n2w    = (const float*)d_in[7];
    const float* n2b    = (const float*)d_in[8];
    const float* fc1_w  = (const float*)d_in[9];
    const float* fc1_b  = (const float*)d_in[10];
    const float* fc2_w  = (const float*)d_in[11];
    const float* fc2_b  = (const float*)d_in[12];
    float* out = (float*)d_out;

    u16* ws16  = (u16*)d_ws;
    u16* xw    = ws16;                        // 12,845,056 u16 (later: attn_out, then h2)
    u16* qkv   = xw + 12845056;               // 38,535,168 u16 (later: proj_out)
    u16* qkvT  = qkv + 38535168;              // 49,152
    u16* projT = qkvT + 49152;                // 16,384
    u16* fc1T  = projT + 16384;               // 65,536
    u16* fc2T  = fc1T + 65536;                // 65,536

    k_wT<<<256, 256, 0, stream>>>(qkv_w, proj_w, fc1_w, fc2_w, qkvT, projT, fc1T, fc2T);
    k_ln1_part<<<25088, 256, 0, stream>>>(x, n1w, n1b, xw);
    dim3 gq(784, 3);
    k_gemm128<<<gq, 256, 0, stream>>>(xw, qkvT, qkv_b, qkv, 384);
    dim3 ga(1024, 4);
    k_attn<<<ga, 256, 0, stream>>>(qkv, xw);                        // attn_out -> xw region
    dim3 gp(784, 1);
    k_gemm128<<<gp, 256, 0, stream>>>(xw, projT, proj_b, qkv, 128); // proj_out -> qkv region
    k_res_ln2<<<25088, 256, 0, stream>>>(qkv, x, n2w, n2b, out /*x1 fp32*/, xw /*h2 bf16*/);
    k_mlp<<<1568, 256, 0, stream>>>(xw /*h2*/, fc1T, fc1_b, fc2T, fc2_b, out /*x1*/, out);
}

// Round 4
// 212.699 us; speedup vs baseline: 2.4081x; 1.1999x over previous
//
#include <hip/hip_runtime.h>

typedef unsigned short u16;
typedef unsigned int u32;
typedef __bf16 bf16x8 __attribute__((ext_vector_type(8)));
typedef float f32x4 __attribute__((ext_vector_type(4)));
typedef u16 u16x8 __attribute__((ext_vector_type(8)));
typedef u16 u16x2 __attribute__((ext_vector_type(2)));

__device__ __forceinline__ float bf2f(u16 u) {
    union { u32 u; float f; } c; c.u = ((u32)u) << 16; return c.f;
}
__device__ __forceinline__ u16 f2bf(float f) {
    union { float f; u32 u; } c; c.f = f;
    u32 r = c.u + 0x7fffu + ((c.u >> 16) & 1u);
    return (u16)(r >> 16);
}
__device__ __forceinline__ bf16x8 ld_frag(const u16* p) {
    return *reinterpret_cast<const bf16x8*>(p);
}

// ---------------- K0: transpose weights to [N][K] (K-contiguous), fp32 -> bf16 ----------------
__global__ __launch_bounds__(256) void k_wT(
    const float* __restrict__ qkv_w, const float* __restrict__ proj_w,
    const float* __restrict__ fc1_w, const float* __restrict__ fc2_w,
    u16* __restrict__ qkvT, u16* __restrict__ projT,
    u16* __restrict__ fc1T, u16* __restrict__ fc2T)
{
    int t = blockIdx.x * 256 + threadIdx.x;          // < 65536
    if (t < 49152) { int k = t / 384, n = t % 384; qkvT[n*128 + k] = f2bf(qkv_w[t]); }
    if (t < 16384) { int k = t / 128, n = t % 128; projT[n*128 + k] = f2bf(proj_w[t]); }
    if (t < 65536) { int k = t / 512, n = t % 512; fc1T[n*128 + k] = f2bf(fc1_w[t]); }
    if (t < 65536) { int k = t / 128, n = t % 128; fc2T[n*512 + k] = f2bf(fc2_w[t]); }
}

// ---------------- K1: LN1 + cyclic shift + window partition (fp32 in, bf16 out) ----------------
__global__ __launch_bounds__(256) void k_ln1_part(
    const float* __restrict__ x, const float* __restrict__ w, const float* __restrict__ b,
    u16* __restrict__ xw)
{
    int wv = threadIdx.x >> 6, l = threadIdx.x & 63;
    int g = blockIdx.x * 4 + wv;                      // < 100352
    int wi = g / 98, n = g % 98;
    int iw = wi & 7, ih = (wi >> 3) & 7, id = (wi >> 6) & 3, bb = wi >> 8;
    int tw = n % 7, tt = n / 7, th = tt % 7, td = tt / 7;
    int d  = (id * 2 + td + 1) & 7;
    int hh = ih * 7 + th + 3; if (hh >= 56) hh -= 56;
    int ww = iw * 7 + tw + 3; if (ww >= 56) ww -= 56;
    long src = ((((long)bb * 8 + d) * 56 + hh) * 56 + ww) * 128;
    float2 v = *(const float2*)(x + src + l * 2);
    float f0 = v.x, f1 = v.y;
    float s = f0 + f1, s2 = f0*f0 + f1*f1;
    #pragma unroll
    for (int o = 32; o; o >>= 1) { s += __shfl_xor(s, o); s2 += __shfl_xor(s2, o); }
    float mean = s * (1.f/128.f);
    float var  = s2 * (1.f/128.f) - mean*mean;
    float rstd = rsqrtf(var + 1e-5f);
    float y0 = (f0 - mean) * rstd * w[l*2]   + b[l*2];
    float y1 = (f1 - mean) * rstd * w[l*2+1] + b[l*2+1];
    u16x2 o2; o2[0] = f2bf(y0); o2[1] = f2bf(y1);
    *(u16x2*)(xw + (long)g * 128 + l * 2) = o2;
}

// ---------------- K2/K4: GEMM  C[M,N] = A[M,128] @ BT[N,128]^T + bias ----------------
__global__ __launch_bounds__(256) void k_gemm128(
    const u16* __restrict__ A, const u16* __restrict__ BT,
    const float* __restrict__ bias, u16* __restrict__ out, int ldo)
{
    __shared__ __align__(16) u16 la[128*136];
    __shared__ __align__(16) u16 lb[128*136];
    int m0 = blockIdx.x * 128, n0 = blockIdx.y * 128;
    int t = threadIdx.x;
    #pragma unroll
    for (int i = 0; i < 8; i++) {
        int u = t + i * 256;
        int r = u >> 4, c = u & 15;
        *(u16x8*)&la[r*136 + c*8] = *(const u16x8*)&A [(long)(m0 + r)*128 + c*8];
        *(u16x8*)&lb[r*136 + c*8] = *(const u16x8*)&BT[(long)(n0 + r)*128 + c*8];
    }
    __syncthreads();
    int wv = t >> 6, l = t & 63;
    int wm = (wv & 1) * 64, wn = (wv >> 1) * 64;
    int lr = l & 15, lk = (l >> 4) * 8;
    f32x4 acc[4][4] = {};
    #pragma unroll
    for (int kk = 0; kk < 4; kk++) {
        bf16x8 af[4], bfr[4];
        #pragma unroll
        for (int mi = 0; mi < 4; mi++) af[mi]  = ld_frag(&la[(wm + mi*16 + lr)*136 + kk*32 + lk]);
        #pragma unroll
        for (int ni = 0; ni < 4; ni++) bfr[ni] = ld_frag(&lb[(wn + ni*16 + lr)*136 + kk*32 + lk]);
        #pragma unroll
        for (int mi = 0; mi < 4; mi++)
            #pragma unroll
            for (int ni = 0; ni < 4; ni++)
                acc[mi][ni] = __builtin_amdgcn_mfma_f32_16x16x32_bf16(af[mi], bfr[ni], acc[mi][ni], 0, 0, 0);
    }
    int rb = (l >> 4) * 4;
    #pragma unroll
    for (int mi = 0; mi < 4; mi++)
        #pragma unroll
        for (int ni = 0; ni < 4; ni++) {
            int col = n0 + wn + ni*16 + lr;
            float bv = bias[col];
            #pragma unroll
            for (int r = 0; r < 4; r++) {
                int row = m0 + wm + mi*16 + rb + r;
                out[(long)row*ldo + col] = f2bf(acc[mi][ni][r] + bv);
            }
        }
}

// ---------------- K3: attention per (window, head) — register-resident scores ----------------
__global__ __launch_bounds__(256) void k_attn(
    const u16* __restrict__ qkv, u16* __restrict__ attn_out)
{
    __shared__ __align__(16) u16 lq[128*40];     // [row][k]  (rows >=98 zero)
    __shared__ __align__(16) u16 lk[128*40];     // [row][k]
    __shared__ __align__(16) u16 lvt[32*136];    // [ch][key] (keys >=98 zero)
    __shared__ __align__(16) u16 lp[4][16*136];  // per-wave P tile [row][key]
    int wi = blockIdx.x, h = blockIdx.y;
    int t = threadIdx.x;
    int wv = t >> 6, l = t & 63;
    const long base = (long)wi * 98 * 384 + h * 32;
    u16* lpw = lp[wv];
    // zero this wave's P buffer (cols 112..127 must stay zero for PV chunk 3)
    {
        u16x8 z8 = {};
        for (int i = l; i < 272; i += 64) *(u16x8*)&lpw[i*8] = z8;
    }
    // stage q,k (zero-padded rows)
    #pragma unroll
    for (int i = 0; i < 4; i++) {
        int u = t + i * 256;                  // < 1024
        int mat = u >> 9, row = (u >> 2) & 127, ch = u & 3;
        u16x8 v = {};
        if (row < 98) v = *(const u16x8*)&qkv[base + (long)row*384 + mat*128 + ch*8];
        u16* dst = mat ? lk : lq;
        *(u16x8*)&dst[row*40 + ch*8] = v;
    }
    // stage v transposed: lvt[ch][key], keys 98..127 zero
    #pragma unroll
    for (int i = 0; i < 2; i++) {
        int u = t + i * 256;                  // < 512
        int row = u >> 2, ch = u & 3;
        u16x8 v = {};
        if (row < 98) v = *(const u16x8*)&qkv[base + (long)row*384 + 256 + ch*8];
        #pragma unroll
        for (int j = 0; j < 8; j++) lvt[(ch*8 + j)*136 + row] = v[j];
    }
    __syncthreads();
    int lr = l & 15, lg = l >> 4, lkk = lg * 8;
    const float scale = 0.17677669529663687f;
    for (int rt = wv; rt < 7; rt += 4) {
        bf16x8 qa = ld_frag(&lq[(rt*16 + lr)*40 + lkk]);
        f32x4 s[7];
        #pragma unroll
        for (int ct = 0; ct < 7; ct++) {
            bf16x8 kb = ld_frag(&lk[(ct*16 + lr)*40 + lkk]);
            f32x4 zz = {0.f, 0.f, 0.f, 0.f};
            s[ct] = __builtin_amdgcn_mfma_f32_16x16x32_bf16(qa, kb, zz, 0, 0, 0);
        }
        #pragma unroll
        for (int ct = 0; ct < 7; ct++) {
            bool valid = (ct < 6) || (lr < 2);
            #pragma unroll
            for (int r = 0; r < 4; r++)
                s[ct][r] = valid ? s[ct][r] * scale : -1e30f;
        }
        f32x4 mx;
        #pragma unroll
        for (int r = 0; r < 4; r++) {
            float m = s[0][r];
            #pragma unroll
            for (int ct = 1; ct < 7; ct++) m = fmaxf(m, s[ct][r]);
            #pragma unroll
            for (int o = 1; o < 16; o <<= 1) m = fmaxf(m, __shfl_xor(m, o));
            mx[r] = m;
        }
        f32x4 sum = {0.f, 0.f, 0.f, 0.f};
        #pragma unroll
        for (int ct = 0; ct < 7; ct++)
            #pragma unroll
            for (int r = 0; r < 4; r++) {
                s[ct][r] = __expf(s[ct][r] - mx[r]);
                sum[r] += s[ct][r];
            }
        #pragma unroll
        for (int r = 0; r < 4; r++) {
            float ss = sum[r];
            #pragma unroll
            for (int o = 1; o < 16; o <<= 1) ss += __shfl_xor(ss, o);
            sum[r] = 1.f / ss;
        }
        #pragma unroll
        for (int ct = 0; ct < 7; ct++)
            #pragma unroll
            for (int r = 0; r < 4; r++)
                lpw[(lg*4 + r)*136 + ct*16 + lr] = f2bf(s[ct][r] * sum[r]);
        #pragma unroll
        for (int ni = 0; ni < 2; ni++) {
            f32x4 acc = {0.f, 0.f, 0.f, 0.f};
            #pragma unroll
            for (int kk = 0; kk < 4; kk++) {
                bf16x8 pa = ld_frag(&lpw[lr*136 + kk*32 + lkk]);
                bf16x8 vb = ld_frag(&lvt[(ni*16 + lr)*136 + kk*32 + lkk]);
                acc = __builtin_amdgcn_mfma_f32_16x16x32_bf16(pa, vb, acc, 0, 0, 0);
            }
            #pragma unroll
            for (int r = 0; r < 4; r++) {
                int row = rt*16 + lg*4 + r;
                if (row < 98)
                    attn_out[((long)wi*98 + row)*128 + h*32 + ni*16 + lr] = f2bf(acc[r]);
            }
        }
    }
}

// ---------------- K5: window reverse + unshift + residual + LN2 ----------------
__global__ __launch_bounds__(256) void k_res_ln2(
    const u16* __restrict__ proj_out, const float* __restrict__ x,
    const float* __restrict__ w2, const float* __restrict__ b2,
    float* __restrict__ x1, u16* __restrict__ h2out)
{
    int wv = threadIdx.x >> 6, l = threadIdx.x & 63;
    int g = blockIdx.x * 4 + wv;                 // natural token id
    int ww = g % 56; int t1 = g / 56;
    int hh = t1 % 56; int t2 = t1 / 56;
    int d = t2 & 7, bb = t2 >> 3;
    int d2 = (d + 7) & 7;
    int hs = hh - 3; if (hs < 0) hs += 56;
    int ws_ = ww - 3; if (ws_ < 0) ws_ += 56;
    int id = d2 >> 1, td = d2 & 1;
    int ih = hs / 7, th = hs % 7;
    int iw = ws_ / 7, tw = ws_ % 7;
    int wi = ((bb*4 + id)*8 + ih)*8 + iw;
    int n  = (td*7 + th)*7 + tw;
    long prow = ((long)wi*98 + n) * 128;
    long nrow = (long)g * 128;
    u16x2 pv = *(const u16x2*)&proj_out[prow + l*2];
    float2 xv = *(const float2*)&x[nrow + l*2];
    float v0 = bf2f(pv[0]) + xv.x;
    float v1 = bf2f(pv[1]) + xv.y;
    float2 o; o.x = v0; o.y = v1;
    *(float2*)&x1[nrow + l*2] = o;
    float s = v0 + v1, s2 = v0*v0 + v1*v1;
    #pragma unroll
    for (int o2 = 32; o2; o2 >>= 1) { s += __shfl_xor(s, o2); s2 += __shfl_xor(s2, o2); }
    float mean = s * (1.f/128.f), var = s2 * (1.f/128.f) - mean*mean;
    float rstd = rsqrtf(var + 1e-5f);
    float y0 = (v0 - mean)*rstd*w2[l*2]   + b2[l*2];
    float y1 = (v1 - mean)*rstd*w2[l*2+1] + b2[l*2+1];
    u16x2 oh; oh[0] = f2bf(y0); oh[1] = f2bf(y1);
    *(u16x2*)&h2out[nrow + l*2] = oh;
}

// ---------------- K6: fused MLP  out = x1 + fc2(silu(fc1(h2))) ----------------
// Hidden dim processed in 8 chunks of 64 units; double-buffered 64x72 chunk LDS.
// Output accumulators register-resident. LDS 35.8 KB -> 4 blocks/CU.
__global__ __launch_bounds__(256, 4) void k_mlp(
    const u16* __restrict__ h2, const u16* __restrict__ fc1T, const float* __restrict__ b1,
    const u16* __restrict__ fc2T, const float* __restrict__ b2,
    const float* __restrict__ x1, float* __restrict__ out)
{
    __shared__ __align__(16) u16 lh[64*136];       // input tile [64][128+pad]
    __shared__ __align__(16) u16 lhc[2][64*72];    // hidden chunk, double-buffered
    int m0 = blockIdx.x * 64;
    int t = threadIdx.x;
    int wv = t >> 6, l = t & 63;
    int lr = l & 15, lg = l >> 4, lk = lg * 8;
    #pragma unroll
    for (int i = 0; i < 4; i++) {
        int u = t + i * 256;                 // < 1024
        int r = u >> 4, c = u & 15;
        *(u16x8*)&lh[r*136 + c*8] = *(const u16x8*)&h2[(long)(m0 + r)*128 + c*8];
    }
    __syncthreads();
    f32x4 oacc[4][2] = {};                   // out cols wv*32 + nt*16 + lr
    for (int ch = 0; ch < 8; ch++) {
        u16* lc = lhc[ch & 1];
        // phase 1: this wave computes hidden units un0..un0+15 for all 64 rows
        int un0 = ch*64 + wv*16;
        bf16x8 bfr[4];
        #pragma unroll
        for (int kk = 0; kk < 4; kk++)
            bfr[kk] = ld_frag(&fc1T[(un0 + lr)*128 + kk*32 + lk]);
        float bv = b1[un0 + lr];
        #pragma unroll
        for (int mt = 0; mt < 4; mt++) {
            f32x4 acc = {0.f, 0.f, 0.f, 0.f};
            #pragma unroll
            for (int kk = 0; kk < 4; kk++) {
                bf16x8 a = ld_frag(&lh[(mt*16 + lr)*136 + kk*32 + lk]);
                acc = __builtin_amdgcn_mfma_f32_16x16x32_bf16(a, bfr[kk], acc, 0, 0, 0);
            }
            #pragma unroll
            for (int r = 0; r < 4; r++) {
                float v = acc[r] + bv;
                v = v / (1.f + __expf(-v));
                lc[(mt*16 + lg*4 + r)*72 + wv*16 + lr] = f2bf(v);
            }
        }
        __syncthreads();                     // chunk ready; also protects buf reuse
        // phase 2: accumulate chunk (K=64) into oacc
        #pragma unroll
        for (int nt = 0; nt < 2; nt++) {
            int col = wv*32 + nt*16 + lr;
            bf16x8 b0 = ld_frag(&fc2T[(long)col*512 + ch*64 + lk]);
            bf16x8 b1f = ld_frag(&fc2T[(long)col*512 + ch*64 + 32 + lk]);
            #pragma unroll
            for (int mt = 0; mt < 4; mt++) {
                bf16x8 a0 = ld_frag(&lc[(mt*16 + lr)*72 + lk]);
                bf16x8 a1 = ld_frag(&lc[(mt*16 + lr)*72 + 32 + lk]);
                oacc[mt][nt] = __builtin_amdgcn_mfma_f32_16x16x32_bf16(a0, b0, oacc[mt][nt], 0, 0, 0);
                oacc[mt][nt] = __builtin_amdgcn_mfma_f32_16x16x32_bf16(a1, b1f, oacc[mt][nt], 0, 0, 0);
            }
        }
    }
    // epilogue: += b2 + x1, write fp32
    #pragma unroll
    for (int nt = 0; nt < 2; nt++) {
        int col = wv*32 + nt*16 + lr;
        float bv = b2[col];
        #pragma unroll
        for (int mt = 0; mt < 4; mt++) {
            #pragma unroll
            for (int r = 0; r < 4; r++) {
                int row = m0 + mt*16 + lg*4 + r;
                out[(long)row*128 + col] = oacc[mt][nt][r] + bv + x1[(long)row*128 + col];
            }
        }
    }
}

extern "C" void kernel_launch(void* const* d_in, const int* in_sizes, int n_in,
                              void* d_out, int out_size, void* d_ws, size_t ws_size,
                              hipStream_t stream)
{
    const float* x      = (const float*)d_in[0];
    const float* n1w    = (const float*)d_in[1];
    const float* n1b    = (const float*)d_in[2];
    const float* qkv_w  = (const float*)d_in[3];
    const float* qkv_b  = (const float*)d_in[4];
    const float* proj_w = (const float*)d_in[5];
    const float* proj_b = (const float*)d_in[6];
    const float* n2w    = (const float*)d_in[7];
    const float* n2b    = (const float*)d_in[8];
    const float* fc1_w  = (const float*)d_in[9];
    const float* fc1_b  = (const float*)d_in[10];
    const float* fc2_w  = (const float*)d_in[11];
    const float* fc2_b  = (const float*)d_in[12];
    float* out = (float*)d_out;

    u16* ws16  = (u16*)d_ws;
    u16* xw    = ws16;                        // 12,845,056 u16 (later: attn_out, then h2)
    u16* qkv   = xw + 12845056;               // 38,535,168 u16 (later: proj_out)
    u16* qkvT  = qkv + 38535168;              // 49,152
    u16* projT = qkvT + 49152;                // 16,384
    u16* fc1T  = projT + 16384;               // 65,536
    u16* fc2T  = fc1T + 65536;                // 65,536

    k_wT<<<256, 256, 0, stream>>>(qkv_w, proj_w, fc1_w, fc2_w, qkvT, projT, fc1T, fc2T);
    k_ln1_part<<<25088, 256, 0, stream>>>(x, n1w, n1b, xw);
    dim3 gq(784, 3);
    k_gemm128<<<gq, 256, 0, stream>>>(xw, qkvT, qkv_b, qkv, 384);
    dim3 ga(1024, 4);
    k_attn<<<ga, 256, 0, stream>>>(qkv, xw);                        // attn_out -> xw region
    dim3 gp(784, 1);
    k_gemm128<<<gp, 256, 0, stream>>>(xw, projT, proj_b, qkv, 128); // proj_out -> qkv region
    k_res_ln2<<<25088, 256, 0, stream>>>(qkv, x, n2w, n2b, out /*x1 fp32*/, xw /*h2 bf16*/);
    k_mlp<<<1568, 256, 0, stream>>>(xw /*h2*/, fc1T, fc1_b, fc2T, fc2_b, out /*x1*/, out);
}